// Round 1
// baseline (430.661 us; speedup 1.0000x reference)
//
#include <hip/hip_runtime.h>
#include <math.h>

#define R_T   16      // sample rows per block
#define JC    8       // feature chunk staged in LDS
#define NCH   8       // 64 features / 8
#define CS_LD 1028    // padded leading dim for centroid chunk
#define N_C   1024
#define M_F   64
#define B_R   32768

__global__ void logprior_kernel(const float* __restrict__ lm, float* __restrict__ lp) {
  __shared__ float red[256];
  const int t = threadIdx.x;
  float v[4];
  float mx = -INFINITY;
#pragma unroll
  for (int i = 0; i < 4; ++i) { v[i] = lm[i * 256 + t]; mx = fmaxf(mx, v[i]); }
  red[t] = mx;
  __syncthreads();
  for (int s = 128; s > 0; s >>= 1) {
    if (t < s) red[t] = fmaxf(red[t], red[t + s]);
    __syncthreads();
  }
  mx = red[0];
  __syncthreads();
  float sum = 0.f;
#pragma unroll
  for (int i = 0; i < 4; ++i) { v[i] -= mx; sum += expf(v[i]); }
  red[t] = sum;
  __syncthreads();
  for (int s = 128; s > 0; s >>= 1) {
    if (t < s) red[t] += red[t + s];
    __syncthreads();
  }
  const float l = logf(red[0]);
#pragma unroll
  for (int i = 0; i < 4; ++i) lp[i * 256 + t] = v[i] - l;
}

__global__ __launch_bounds__(256, 2) void rmm_main(
    const float* __restrict__ samples, const float* __restrict__ mask,
    const float* __restrict__ centroids, const float* __restrict__ sd,
    const float* __restrict__ lp_g, float* __restrict__ out) {
  __shared__ float cs[JC * CS_LD];
  __shared__ float u_s[M_F * R_T];
  __shared__ float w_s[M_F * R_T];
  __shared__ float ad_s[R_T];
  __shared__ float red_s[R_T * 4];

  const int t = threadIdx.x;
  const int b0 = blockIdx.x * R_T;

  // ---- per-row u = (mask/sd)^2, w = 2*u*sample, A_d = sum((m*A)^2) ----
  {
    const int r  = t >> 4;
    const int j4 = (t & 15) << 2;
    const float4 s4 = *(const float4*)(samples + (size_t)(b0 + r) * M_F + j4);
    const float4 m4 = *(const float4*)(mask + (size_t)(b0 + r) * M_F + j4);
    const float4 d4 = *(const float4*)(sd + j4);
    const float sa[4] = {s4.x, s4.y, s4.z, s4.w};
    const float ma[4] = {m4.x, m4.y, m4.z, m4.w};
    const float da[4] = {d4.x, d4.y, d4.z, d4.w};
    float ad = 0.f;
#pragma unroll
    for (int k = 0; k < 4; ++k) {
      float mm = ma[k] / da[k];
      float uu = mm * mm;          // sq_mask
      float mA = mm * sa[k];
      ad = fmaf(mA, mA, ad);       // A_d partial
      u_s[(j4 + k) * R_T + r] = uu;
      w_s[(j4 + k) * R_T + r] = 2.0f * (uu * sa[k]);  // 2 * (sq_mask * A)
    }
#pragma unroll
    for (int off = 8; off >= 1; off >>= 1) ad += __shfl_xor(ad, off, 16);
    if ((t & 15) == 0) ad_s[r] = ad;
  }

  const float4 lpv = *(const float4*)(lp_g + (t << 2));
  const float lp[4] = {lpv.x, lpv.y, lpv.z, lpv.w};

  float acc[R_T][4];
#pragma unroll
  for (int r = 0; r < R_T; ++r)
#pragma unroll
    for (int c = 0; c < 4; ++c) acc[r][c] = 0.f;

  __syncthreads();

  // ---- main loop: acc = B_d - 2*cross, via c*(u*c - w) ----
  for (int ch = 0; ch < NCH; ++ch) {
#pragma unroll
    for (int i = 0; i < 8; ++i) {
      int lin = i * 256 + t;
      int n   = lin >> 1;
      int j4  = (lin & 1) << 2;
      const float4 c4 = *(const float4*)(centroids + (size_t)n * M_F + ch * JC + j4);
      cs[(j4 + 0) * CS_LD + n] = c4.x;
      cs[(j4 + 1) * CS_LD + n] = c4.y;
      cs[(j4 + 2) * CS_LD + n] = c4.z;
      cs[(j4 + 3) * CS_LD + n] = c4.w;
    }
    __syncthreads();

#pragma unroll
    for (int jj = 0; jj < JC; ++jj) {
      const float4 cv = *(const float4*)(&cs[jj * CS_LD + (t << 2)]);
      const float ca[4] = {cv.x, cv.y, cv.z, cv.w};
      float uu[R_T], ww[R_T];
#pragma unroll
      for (int k = 0; k < 4; ++k) {
        *(float4*)&uu[4 * k] = *(const float4*)(&u_s[(ch * JC + jj) * R_T + 4 * k]);
        *(float4*)&ww[4 * k] = *(const float4*)(&w_s[(ch * JC + jj) * R_T + 4 * k]);
      }
#pragma unroll
      for (int r = 0; r < R_T; ++r) {
#pragma unroll
        for (int c = 0; c < 4; ++c) {
          float tmp = fmaf(uu[r], ca[c], -ww[r]);
          acc[r][c] = fmaf(ca[c], tmp, acc[r][c]);
        }
      }
    }
    __syncthreads();
  }

  // ---- epilogue: logits -> softmax -> truncate -> renorm -> log ----
  const int wid  = t >> 6;
  const int lane = t & 63;

  float pm[R_T];
#pragma unroll
  for (int r = 0; r < R_T; ++r) {
    const float ad = ad_s[r];
    float m = -INFINITY;
#pragma unroll
    for (int c = 0; c < 4; ++c) {
      float dist = fmaxf(ad + acc[r][c], 0.0f);
      float lgt  = lp[c] - 0.5f * dist;
      acc[r][c]  = lgt;
      m = fmaxf(m, lgt);
    }
#pragma unroll
    for (int off = 1; off < 64; off <<= 1) m = fmaxf(m, __shfl_xor(m, off, 64));
    pm[r] = m;
  }
  if (lane == 0) {
#pragma unroll
    for (int r = 0; r < R_T; ++r) red_s[r * 4 + wid] = pm[r];
  }
  __syncthreads();
#pragma unroll
  for (int r = 0; r < R_T; ++r) {
    const float4 q = *(const float4*)(&red_s[r * 4]);
    pm[r] = fmaxf(fmaxf(q.x, q.y), fmaxf(q.z, q.w));
  }
  __syncthreads();

  float ps[R_T];
#pragma unroll
  for (int r = 0; r < R_T; ++r) {
    float s = 0.f;
#pragma unroll
    for (int c = 0; c < 4; ++c) {
      float e = expf(acc[r][c] - pm[r]);
      acc[r][c] = e;
      s += e;
    }
#pragma unroll
    for (int off = 1; off < 64; off <<= 1) s += __shfl_xor(s, off, 64);
    ps[r] = s;
  }
  if (lane == 0) {
#pragma unroll
    for (int r = 0; r < R_T; ++r) red_s[r * 4 + wid] = ps[r];
  }
  __syncthreads();
#pragma unroll
  for (int r = 0; r < R_T; ++r) {
    const float4 q = *(const float4*)(&red_s[r * 4]);
    ps[r] = (q.x + q.y) + (q.z + q.w);
  }
  __syncthreads();

  float thr[R_T], qs[R_T];
#pragma unroll
  for (int r = 0; r < R_T; ++r) {
    const float S1 = ps[r];
    thr[r] = 0.05f * (1.0f / S1);   // 0.05 * max(pdf), max pdf == fl(1/S1)
    float s2 = 0.f;
#pragma unroll
    for (int c = 0; c < 4; ++c) {
      float p = acc[r][c] / S1;     // elementwise IEEE div to match np
      acc[r][c] = p;
      s2 += (p > thr[r]) ? p : 0.0f;
    }
#pragma unroll
    for (int off = 1; off < 64; off <<= 1) s2 += __shfl_xor(s2, off, 64);
    qs[r] = s2;
  }
  if (lane == 0) {
#pragma unroll
    for (int r = 0; r < R_T; ++r) red_s[r * 4 + wid] = qs[r];
  }
  __syncthreads();
#pragma unroll
  for (int r = 0; r < R_T; ++r) {
    const float4 q = *(const float4*)(&red_s[r * 4]);
    qs[r] = (q.x + q.y) + (q.z + q.w);
  }

#pragma unroll
  for (int r = 0; r < R_T; ++r) {
    float4 po, lo;
    float* pp = &po.x;
    float* ll = &lo.x;
#pragma unroll
    for (int c = 0; c < 4; ++c) {
      float p  = acc[r][c];
      float pf = (p > thr[r]) ? (p / qs[r]) : 0.0f;
      pp[c] = pf;
      ll[c] = logf(pf + 1e-20f);
    }
    const size_t base = (size_t)(b0 + r) * N_C + (size_t)(t << 2);
    *(float4*)(out + base) = po;
    *(float4*)(out + (size_t)B_R * N_C + base) = lo;
  }
}

extern "C" void kernel_launch(void* const* d_in, const int* in_sizes, int n_in,
                              void* d_out, int out_size, void* d_ws, size_t ws_size,
                              hipStream_t stream) {
  const float* samples   = (const float*)d_in[0];
  const float* mask      = (const float*)d_in[1];
  const float* centroids = (const float*)d_in[2];
  const float* sd        = (const float*)d_in[3];
  const float* lm        = (const float*)d_in[4];
  float* out = (float*)d_out;
  float* lp  = (float*)d_ws;   // 1024 floats of scratch

  logprior_kernel<<<1, 256, 0, stream>>>(lm, lp);
  rmm_main<<<B_R / R_T, 256, 0, stream>>>(samples, mask, centroids, sd, lp, out);
}

// Round 3
// 344.087 us; speedup vs baseline: 1.2516x; 1.2516x over previous
//
#include <hip/hip_runtime.h>
#include <math.h>

#define N_C 1024
#define M_F 64
#define B_R 32768
#define R_B 16       // rows per block
#define LDX 132      // padded fp32 leading dim for X in LDS

typedef short bf16x8 __attribute__((ext_vector_type(8)));
typedef float f32x4 __attribute__((ext_vector_type(4)));

__device__ __forceinline__ short f2bf(float x) {
  unsigned b = __float_as_uint(x);
  b += 0x7fffu + ((b >> 16) & 1u);   // RTNE (finite inputs only)
  return (short)(b >> 16);
}
__device__ __forceinline__ float bf2f(short h) {
  return __uint_as_float(((unsigned)(unsigned short)h) << 16);
}

__global__ void logprior_kernel(const float* __restrict__ lm, float* __restrict__ lp) {
  __shared__ float red[256];
  const int t = threadIdx.x;
  float v[4];
  float mx = -INFINITY;
#pragma unroll
  for (int i = 0; i < 4; ++i) { v[i] = lm[i * 256 + t]; mx = fmaxf(mx, v[i]); }
  red[t] = mx;
  __syncthreads();
  for (int s = 128; s > 0; s >>= 1) {
    if (t < s) red[t] = fmaxf(red[t], red[t + s]);
    __syncthreads();
  }
  mx = red[0];
  __syncthreads();
  float sum = 0.f;
#pragma unroll
  for (int i = 0; i < 4; ++i) { v[i] -= mx; sum += expf(v[i]); }
  red[t] = sum;
  __syncthreads();
  for (int s = 128; s > 0; s >>= 1) {
    if (t < s) red[t] += red[t + s];
    __syncthreads();
  }
  const float l = logf(red[0]);
#pragma unroll
  for (int i = 0; i < 4; ++i) lp[i * 256 + t] = v[i] - l;
}

// Exact 3-way bf16 split of Y = [C | C^2], MFMA B-frag swizzled:
// blob[(s*64 + c)*64 + lane] holds Y[n = c*16+(lane&15)][k = s*32+(lane>>4)*8 ..+7]
__global__ void prep_y(const float* __restrict__ centroids,
                       bf16x8* __restrict__ yh, bf16x8* __restrict__ ym,
                       bf16x8* __restrict__ yl) {
  const int tid = blockIdx.x * 256 + threadIdx.x;  // 0..16383
  const int l = tid & 63;
  const int c = (tid >> 6) & 63;
  const int s = tid >> 12;
  const int n = c * 16 + (l & 15);
  const int k0 = s * 32 + (l >> 4) * 8;
  bf16x8 h, mid, lo;
#pragma unroll
  for (int j = 0; j < 8; ++j) {
    const int k = k0 + j;
    float y;
    if (k < 64) {
      y = centroids[n * M_F + k];
    } else {
      const float cc = centroids[n * M_F + (k - 64)];
      y = cc * cc;
    }
    const short hh = f2bf(y);
    const float r1 = y - bf2f(hh);        // exact
    const short mm = f2bf(r1);
    const float r2 = r1 - bf2f(mm);       // exact, fits 8 bits
    h[j] = hh;
    mid[j] = mm;
    lo[j] = f2bf(r2);                     // exact
  }
  const int blob = (s * 64 + c) * 64 + l;
  yh[blob] = h;
  ym[blob] = mid;
  yl[blob] = lo;
}

__global__ __launch_bounds__(256, 3) void rmm_main(
    const float* __restrict__ samples, const float* __restrict__ mask,
    const float* __restrict__ sd, const float* __restrict__ lp_g,
    const bf16x8* __restrict__ yh_g, const bf16x8* __restrict__ ym_g,
    const bf16x8* __restrict__ yl_g, float* __restrict__ out) {
  __shared__ float xs[R_B * LDX];   // X fp32, [row][k], k<64: -2uA, k>=64: u
  __shared__ float lp_s[N_C];
  __shared__ float ad_s[R_B];
  __shared__ float red_s[R_B * 4];

  const int t = threadIdx.x;
  const int b0 = blockIdx.x * R_B;
  const int w = t >> 6;   // wave id: cols [w*256, w*256+256)
  const int l = t & 63;
  const int m = l & 15;   // tile row (A) / tile col (C)
  const int q = l >> 4;   // quad

  *(float4*)(lp_s + (t << 2)) = *(const float4*)(lp_g + (t << 2));

  // ---- build X rows, A_d = sum((m*A)^2) ----
  {
    const int r = t >> 4;
    const int j4 = (t & 15) << 2;
    const float4 s4 = *(const float4*)(samples + (size_t)(b0 + r) * M_F + j4);
    const float4 m4 = *(const float4*)(mask + (size_t)(b0 + r) * M_F + j4);
    const float4 d4 = *(const float4*)(sd + j4);
    const float sa[4] = {s4.x, s4.y, s4.z, s4.w};
    const float ma[4] = {m4.x, m4.y, m4.z, m4.w};
    const float da[4] = {d4.x, d4.y, d4.z, d4.w};
    float ad = 0.f;
#pragma unroll
    for (int k = 0; k < 4; ++k) {
      const float mm = ma[k] / da[k];
      const float uu = mm * mm;
      const float mA = mm * sa[k];
      ad = fmaf(mA, mA, ad);
      xs[r * LDX + j4 + k] = -2.0f * (uu * sa[k]);
      xs[r * LDX + 64 + j4 + k] = uu;
    }
#pragma unroll
    for (int off = 1; off < 16; off <<= 1) ad += __shfl_xor(ad, off, 64);
    if ((t & 15) == 0) ad_s[r] = ad;
  }

  f32x4 acc[16];
#pragma unroll
  for (int c = 0; c < 16; ++c) acc[c] = (f32x4){0.f, 0.f, 0.f, 0.f};

  __syncthreads();

  // ---- K loop: 4 steps of K=32, exact-split bf16x8 products ----
#pragma unroll 1
  for (int s = 0; s < 4; ++s) {
    const float* xp = &xs[m * LDX + s * 32 + q * 8];
    float av[8];
    *(float4*)&av[0] = *(const float4*)xp;
    *(float4*)&av[4] = *(const float4*)(xp + 4);
    bf16x8 ah, am, al;
#pragma unroll
    for (int j = 0; j < 8; ++j) {
      const short hh = f2bf(av[j]);
      const float r1 = av[j] - bf2f(hh);   // exact
      const short mm = f2bf(r1);
      const float r2 = r1 - bf2f(mm);      // exact
      ah[j] = hh;
      am[j] = mm;
      al[j] = f2bf(r2);                    // exact
    }

    const size_t base = (size_t)(s * 64 + w * 16) * 64 + l;
    const bf16x8* yh = yh_g + base;
    const bf16x8* ym = ym_g + base;
    const bf16x8* yl = yl_g + base;

    bf16x8 bh[2], bm[2], bl[2];
#pragma unroll
    for (int p = 0; p < 2; ++p) {
      bh[p] = yh[p * 64];
      bm[p] = ym[p * 64];
      bl[p] = yl[p * 64];
    }

#pragma unroll
    for (int c = 0; c < 16; ++c) {
      const bf16x8 cbh = bh[c & 1];
      const bf16x8 cbm = bm[c & 1];
      const bf16x8 cbl = bl[c & 1];
      if (c + 2 < 16) {
        bh[c & 1] = yh[(c + 2) * 64];
        bm[c & 1] = ym[(c + 2) * 64];
        bl[c & 1] = yl[(c + 2) * 64];
      }
      // small -> large; only Xl*Yl dropped (<= 2^-36 rel per term)
      acc[c] = __builtin_amdgcn_mfma_f32_16x16x32_bf16(am, cbl, acc[c], 0, 0, 0);
      acc[c] = __builtin_amdgcn_mfma_f32_16x16x32_bf16(al, cbm, acc[c], 0, 0, 0);
      acc[c] = __builtin_amdgcn_mfma_f32_16x16x32_bf16(ah, cbl, acc[c], 0, 0, 0);
      acc[c] = __builtin_amdgcn_mfma_f32_16x16x32_bf16(am, cbm, acc[c], 0, 0, 0);
      acc[c] = __builtin_amdgcn_mfma_f32_16x16x32_bf16(al, cbh, acc[c], 0, 0, 0);
      acc[c] = __builtin_amdgcn_mfma_f32_16x16x32_bf16(ah, cbm, acc[c], 0, 0, 0);
      acc[c] = __builtin_amdgcn_mfma_f32_16x16x32_bf16(am, cbh, acc[c], 0, 0, 0);
      acc[c] = __builtin_amdgcn_mfma_f32_16x16x32_bf16(ah, cbh, acc[c], 0, 0, 0);
    }
  }

  // ---- epilogue: C/D layout row = q*4+g, col = w*256 + c*16 + m ----
  float adv[4];
#pragma unroll
  for (int g = 0; g < 4; ++g) adv[g] = ad_s[q * 4 + g];
  float lpv[16];
#pragma unroll
  for (int c = 0; c < 16; ++c) lpv[c] = lp_s[w * 256 + c * 16 + m];

#pragma unroll
  for (int c = 0; c < 16; ++c)
#pragma unroll
    for (int g = 0; g < 4; ++g) {
      const float dist = fmaxf(adv[g] + acc[c][g], 0.0f);
      acc[c][g] = lpv[c] - 0.5f * dist;
    }

  float mx[4];
#pragma unroll
  for (int g = 0; g < 4; ++g) {
    float v = acc[0][g];
#pragma unroll
    for (int c = 1; c < 16; ++c) v = fmaxf(v, acc[c][g]);
#pragma unroll
    for (int off = 1; off < 16; off <<= 1) v = fmaxf(v, __shfl_xor(v, off, 64));
    mx[g] = v;
  }
  if (m == 0) {
#pragma unroll
    for (int g = 0; g < 4; ++g) red_s[(q * 4 + g) * 4 + w] = mx[g];
  }
  __syncthreads();
#pragma unroll
  for (int g = 0; g < 4; ++g) {
    const float4 rv = *(const float4*)(&red_s[(q * 4 + g) * 4]);
    mx[g] = fmaxf(fmaxf(rv.x, rv.y), fmaxf(rv.z, rv.w));
  }
  __syncthreads();

  float sm[4];
#pragma unroll
  for (int g = 0; g < 4; ++g) {
    float ssum = 0.f;
#pragma unroll
    for (int c = 0; c < 16; ++c) {
      const float e = expf(acc[c][g] - mx[g]);
      acc[c][g] = e;
      ssum += e;
    }
#pragma unroll
    for (int off = 1; off < 16; off <<= 1) ssum += __shfl_xor(ssum, off, 64);
    sm[g] = ssum;
  }
  if (m == 0) {
#pragma unroll
    for (int g = 0; g < 4; ++g) red_s[(q * 4 + g) * 4 + w] = sm[g];
  }
  __syncthreads();
#pragma unroll
  for (int g = 0; g < 4; ++g) {
    const float4 rv = *(const float4*)(&red_s[(q * 4 + g) * 4]);
    sm[g] = (rv.x + rv.y) + (rv.z + rv.w);
  }
  __syncthreads();

  float thr[4], qs[4];
#pragma unroll
  for (int g = 0; g < 4; ++g) {
    const float S1 = sm[g];
    thr[g] = 0.05f * (1.0f / S1);
    float s2 = 0.f;
#pragma unroll
    for (int c = 0; c < 16; ++c) {
      const float p = acc[c][g] / S1;   // IEEE div, matches np
      acc[c][g] = p;
      s2 += (p > thr[g]) ? p : 0.0f;
    }
#pragma unroll
    for (int off = 1; off < 16; off <<= 1) s2 += __shfl_xor(s2, off, 64);
    qs[g] = s2;
  }
  if (m == 0) {
#pragma unroll
    for (int g = 0; g < 4; ++g) red_s[(q * 4 + g) * 4 + w] = qs[g];
  }
  __syncthreads();
#pragma unroll
  for (int g = 0; g < 4; ++g) {
    const float4 rv = *(const float4*)(&red_s[(q * 4 + g) * 4]);
    qs[g] = (rv.x + rv.y) + (rv.z + rv.w);
  }

  const size_t colbase = (size_t)(w * 256 + m);
#pragma unroll
  for (int g = 0; g < 4; ++g) {
    float* orow = out + (size_t)(b0 + q * 4 + g) * N_C + colbase;
    float* lrow = orow + (size_t)B_R * N_C;
#pragma unroll
    for (int c = 0; c < 16; ++c) {
      const float p = acc[c][g];
      const float pf = (p > thr[g]) ? (p / qs[g]) : 0.0f;
      orow[c * 16] = pf;
      lrow[c * 16] = logf(pf + 1e-20f);
    }
  }
}

extern "C" void kernel_launch(void* const* d_in, const int* in_sizes, int n_in,
                              void* d_out, int out_size, void* d_ws, size_t ws_size,
                              hipStream_t stream) {
  const float* samples   = (const float*)d_in[0];
  const float* mask      = (const float*)d_in[1];
  const float* centroids = (const float*)d_in[2];
  const float* sd        = (const float*)d_in[3];
  const float* lm        = (const float*)d_in[4];
  float* out = (float*)d_out;

  char* ws = (char*)d_ws;
  float* lp  = (float*)ws;                          // 4 KB
  bf16x8* yh = (bf16x8*)(ws + 4096);                // 256 KB
  bf16x8* ym = (bf16x8*)(ws + 4096 + 262144);       // 256 KB
  bf16x8* yl = (bf16x8*)(ws + 4096 + 2 * 262144);   // 256 KB

  logprior_kernel<<<1, 256, 0, stream>>>(lm, lp);
  prep_y<<<64, 256, 0, stream>>>(centroids, yh, ym, yl);
  rmm_main<<<B_R / R_B, 256, 0, stream>>>(samples, mask, sd, lp, yh, ym, yl, out);
}